// Round 18
// baseline (16.991 us; speedup 1.0000x reference)
//
#include <hip/hip_runtime.h>
#include <stdint.h>

#define HH 512
#define WW 512
#define NIMG 16
#define EPSF 1e-5f
#define INV81 (1.0f / 81.0f)

// lane l receives lane l-1's value; lane 0 -> 0  (wave_shr:1, bound_ctrl=1)
__device__ __forceinline__ float dpp_shr1(float x) {
    return __int_as_float(__builtin_amdgcn_update_dpp(
        0, __float_as_int(x), 0x138, 0xF, 0xF, true));
}
// lane l receives lane l+1's value; lane 63 -> 0  (wave_shl:1, bound_ctrl=1)
__device__ __forceinline__ float dpp_shl1(float x) {
    return __int_as_float(__builtin_amdgcn_update_dpp(
        0, __float_as_int(x), 0x130, 0xF, 0xF, true));
}

// One global_load_lds_dwordx4: dest = wave-uniform LDS base + lane*16,
// src = per-lane global address. Replaces load->VGPR->ds_write staging.
__device__ __forceinline__ void gl_lds16(const float* g, float4* ldsbase) {
    __builtin_amdgcn_global_load_lds(
        (const __attribute__((address_space(1))) void*)g,
        (__attribute__((address_space(3))) void*)ldsbase,
        16, 0, 0);
}

// R18 = R17 (1024 blocks x 8 waves, one (image, 8-row strip), 16-slot 64KB
// LDS, conflict-free float4 layout, DPP hbox, XCD swizzle, plain-store
// partials) with ONE change: prologue staging via global_load_lds DMA
// (4 instructions per row: imgA/imgB x region0/region1), removing the
// VGPR round-trip and its vmcnt->ds_write dependent chain. Zero-rows
// (wave-uniform) fall back to plain ds_write of zeros.
__global__ __launch_bounds__(512, 4) void ncc_main(const float* __restrict__ Iin,
                                                   const float* __restrict__ Jin,
                                                   float* __restrict__ part) {
    __shared__ float4 ring4[16][2][128];  // 64 KB: [slot][img][A(0..63)|B(64..127)]
    __shared__ float wsum[8];

    const int tid  = threadIdx.x;
    const int lane = tid & 63;
    const int w    = tid >> 6;           // wave id 0..7
    const int xcd  = blockIdx.x & 7;     // HW round-robin XCD
    const int idx  = blockIdx.x >> 3;    // 0..127 within XCD
    const int n    = (xcd << 1) | (idx >> 6);   // image (2 per XCD = L2-sized)
    const int y0   = (idx & 63) << 3;           // strip base output row (8 rows)
    const int c0   = lane << 3;          // 8 cols per lane (global addressing)

    const float* Ib = Iin + (size_t)n * (HH * WW);
    const float* Jb = Jin + (size_t)n * (HH * WW);

    // Stage row rr (rr = row-(y0-4), in [0,16)) into slot rr via DMA.
    auto stage = [&](int rr) {
        const int r = y0 - 4 + rr;
        if (r >= 0 && r < HH) {           // wave-uniform
            const float* rI = Ib + (size_t)r * WW + c0;   // per-lane src
            const float* rJ = Jb + (size_t)r * WW + c0;
            gl_lds16(rI,     &ring4[rr][0][0]);    // I cols 8l..8l+3  -> [lane]
            gl_lds16(rI + 4, &ring4[rr][0][64]);   // I cols 8l+4..8l+7-> [64+lane]
            gl_lds16(rJ,     &ring4[rr][1][0]);
            gl_lds16(rJ + 4, &ring4[rr][1][64]);
        } else {
            const float4 z = make_float4(0.f, 0.f, 0.f, 0.f);
            ring4[rr][0][lane]      = z;
            ring4[rr][0][64 + lane] = z;
            ring4[rr][1][lane]      = z;
            ring4[rr][1][64 + lane] = z;
        }
    };

    // Prologue: 16 rows, 2 per wave, 4 DMA instrs each; one barrier.
    stage(2 * w);
    stage(2 * w + 1);
    __syncthreads();                      // vmcnt(0)+lgkmcnt(0): all rows landed

    auto hbox = [&](const float (&C)[8], float (&B)[8]) {
        float H[16];
        #pragma unroll
        for (int k = 0; k < 4; ++k) H[k] = dpp_shr1(C[4 + k]);   // lane-1 cols
        #pragma unroll
        for (int k = 0; k < 8; ++k) H[4 + k] = C[k];
        #pragma unroll
        for (int k = 0; k < 4; ++k) H[12 + k] = dpp_shl1(C[k]);  // lane+1 cols
        float s = ((H[0] + H[1]) + (H[2] + H[3])) + ((H[4] + H[5]) + (H[6] + H[7])) + H[8];
        B[0] = s;
        #pragma unroll
        for (int i = 1; i < 8; ++i) { s += H[i + 8] - H[i - 1]; B[i] = s; }
    };

    float local = 0.f;

    // This wave's output row: window slots w .. w+8 (all resident).
    {
        float SI[8], SJ[8], SI2[8], SJ2[8], SIJ[8];
        #pragma unroll
        for (int c = 0; c < 8; ++c) { SI[c]=0.f; SJ[c]=0.f; SI2[c]=0.f; SJ2[c]=0.f; SIJ[c]=0.f; }
        #pragma unroll
        for (int k = 0; k < 9; ++k) {
            const int sl = w + k;
            const float4 i0 = ring4[sl][0][lane];
            const float4 i1 = ring4[sl][0][64 + lane];
            const float4 j0 = ring4[sl][1][lane];
            const float4 j1 = ring4[sl][1][64 + lane];
            const float ai[8] = {i0.x, i0.y, i0.z, i0.w, i1.x, i1.y, i1.z, i1.w};
            const float bj[8] = {j0.x, j0.y, j0.z, j0.w, j1.x, j1.y, j1.z, j1.w};
            #pragma unroll
            for (int c = 0; c < 8; ++c) {
                SI[c] += ai[c];  SJ[c] += bj[c];
                SI2[c] = fmaf(ai[c], ai[c], SI2[c]);
                SJ2[c] = fmaf(bj[c], bj[c], SJ2[c]);
                SIJ[c] = fmaf(ai[c], bj[c], SIJ[c]);
            }
        }
        float BI[8], BJ[8], BI2[8], BJ2[8], BIJ[8];
        hbox(SI, BI); hbox(SJ, BJ); hbox(SI2, BI2); hbox(SJ2, BJ2); hbox(SIJ, BIJ);
        #pragma unroll
        for (int c = 0; c < 8; ++c) {
            const float tI = BI[c] * INV81;
            const float tJ = BJ[c] * INV81;
            const float cross = fmaf(-tI, BJ[c], BIJ[c]);
            const float Iv    = fmaf(-tI, BI[c], BI2[c]);
            const float Jv    = fmaf(-tJ, BJ[c], BJ2[c]);
            const float den   = fmaf(Iv, Jv, EPSF);
            local = fmaf(cross * cross, __builtin_amdgcn_rcpf(den), local);
        }
    }

    // wave reduction -> block reduction -> one plain store per block
    #pragma unroll
    for (int off = 32; off > 0; off >>= 1) local += __shfl_down(local, off);
    if (lane == 0) wsum[w] = local;
    __syncthreads();
    if (tid == 0) {
        float b = 0.f;
        #pragma unroll
        for (int k = 0; k < 8; ++k) b += wsum[k];
        part[blockIdx.x] = b;             // distinct address per block
    }
}

// 1 block, 1024 threads: reduce 1024 partials, write the scalar output.
__global__ __launch_bounds__(1024) void ncc_final(const float* __restrict__ part,
                                                  float* __restrict__ out) {
    __shared__ float s[16];
    const int tid  = threadIdx.x;
    const int lane = tid & 63;
    const int w    = tid >> 6;
    float v = part[tid];
    #pragma unroll
    for (int off = 32; off > 0; off >>= 1) v += __shfl_down(v, off);
    if (lane == 0) s[w] = v;
    __syncthreads();
    if (tid == 0) {
        float t = 0.f;
        #pragma unroll
        for (int k = 0; k < 16; ++k) t += s[k];
        out[0] = 1.0f - t * (1.0f / (float)((size_t)NIMG * HH * WW));
    }
}

extern "C" void kernel_launch(void* const* d_in, const int* in_sizes, int n_in,
                              void* d_out, int out_size, void* d_ws, size_t ws_size,
                              hipStream_t stream) {
    const float* I = (const float*)d_in[0];
    const float* J = (const float*)d_in[1];
    float* out  = (float*)d_out;
    float* part = (float*)d_ws;          // 1024 floats, fully rewritten each call

    // 1024 blocks = 16 images x 64 strips of 8 rows; 8 waves/block;
    // 64 KB LDS -> 2 resident/CU (4 waves/SIMD).
    ncc_main<<<1024, 512, 0, stream>>>(I, J, part);
    ncc_final<<<1, 1024, 0, stream>>>(part, out);
}

// Round 19
// 16.086 us; speedup vs baseline: 1.0563x; 1.0563x over previous
//
#include <hip/hip_runtime.h>

#define HH 512
#define WW 512
#define NIMG 16
#define EPSF 1e-5f
#define INV81 (1.0f / 81.0f)

// lane l receives lane l-1's value; lane 0 -> 0  (wave_shr:1, bound_ctrl=1)
__device__ __forceinline__ float dpp_shr1(float x) {
    return __int_as_float(__builtin_amdgcn_update_dpp(
        0, __float_as_int(x), 0x138, 0xF, 0xF, true));
}
// lane l receives lane l+1's value; lane 63 -> 0  (wave_shl:1, bound_ctrl=1)
__device__ __forceinline__ float dpp_shl1(float x) {
    return __int_as_float(__builtin_amdgcn_update_dpp(
        0, __float_as_int(x), 0x130, 0xF, 0xF, true));
}

// FINAL (= R17, best measured: 15.92 us, absmax 0). Single-phase blocks:
// 1024 blocks x 8 waves, one (image, 8-row strip) each. 16-slot LDS buffer
// (64 KB -> 2 blocks/CU, 4 waves/SIMD): each wave loads 2 rows -> ONE
// barrier -> each wave computes one output row (9-row window sums from
// conflict-free float4 LDS, DPP-halo horizontal 9-box, cc) -> reduce ->
// plain store part[bid] (NO same-address atomics: that was -13us).
// Occupancy > per-thread efficiency for this latency-bound op (R16 lesson);
// VGPR-staged prologue beats global_load_lds DMA here (R18 lesson).
__global__ __launch_bounds__(512, 4) void ncc_main(const float* __restrict__ Iin,
                                                   const float* __restrict__ Jin,
                                                   float* __restrict__ part) {
    __shared__ float4 ring4[16][2][128];  // 64 KB: [slot][img][A(0..63)|B(64..127)]
    __shared__ float wsum[8];

    const int tid  = threadIdx.x;
    const int lane = tid & 63;
    const int w    = tid >> 6;           // wave id 0..7
    const int xcd  = blockIdx.x & 7;     // HW round-robin XCD
    const int idx  = blockIdx.x >> 3;    // 0..127 within XCD
    const int n    = (xcd << 1) | (idx >> 6);   // image (2 per XCD = L2-sized)
    const int y0   = (idx & 63) << 3;           // strip base output row (8 rows)
    const int c0   = lane << 3;          // 8 cols per lane (global addressing)

    const float* Ib = Iin + (size_t)n * (HH * WW);
    const float* Jb = Jin + (size_t)n * (HH * WW);

    // rr = row - (y0-4), rr in [0,16)
    auto gload = [&](int rr, float4& a0, float4& a1, float4& b0, float4& b1) {
        const int r = y0 - 4 + rr;
        if (r >= 0 && r < HH) {           // wave-uniform
            const float4* pI = (const float4*)(Ib + (size_t)r * WW + c0);
            const float4* pJ = (const float4*)(Jb + (size_t)r * WW + c0);
            a0 = pI[0]; a1 = pI[1]; b0 = pJ[0]; b1 = pJ[1];
        } else {
            a0 = a1 = b0 = b1 = make_float4(0.f, 0.f, 0.f, 0.f);
        }
    };
    auto swrite = [&](int rr, const float4& a0, const float4& a1,
                              const float4& b0, const float4& b1) {
        ring4[rr][0][lane]      = a0;     // A region: byte 16*lane
        ring4[rr][0][64 + lane] = a1;     // B region: byte 1024+16*lane
        ring4[rr][1][lane]      = b0;
        ring4[rr][1][64 + lane] = b1;
    };

    // Prologue: 16 rows (rr 0..15), 2 per wave, independent; one barrier.
    {
        float4 p0, p1, q0, q1, r0, r1, s0, s1;
        gload(2 * w,     p0, p1, q0, q1);
        gload(2 * w + 1, r0, r1, s0, s1);
        swrite(2 * w,     p0, p1, q0, q1);
        swrite(2 * w + 1, r0, r1, s0, s1);
    }
    __syncthreads();                      // the only barrier before reduce

    auto hbox = [&](const float (&C)[8], float (&B)[8]) {
        float H[16];
        #pragma unroll
        for (int k = 0; k < 4; ++k) H[k] = dpp_shr1(C[4 + k]);   // lane-1 cols
        #pragma unroll
        for (int k = 0; k < 8; ++k) H[4 + k] = C[k];
        #pragma unroll
        for (int k = 0; k < 4; ++k) H[12 + k] = dpp_shl1(C[k]);  // lane+1 cols
        float s = ((H[0] + H[1]) + (H[2] + H[3])) + ((H[4] + H[5]) + (H[6] + H[7])) + H[8];
        B[0] = s;
        #pragma unroll
        for (int i = 1; i < 8; ++i) { s += H[i + 8] - H[i - 1]; B[i] = s; }
    };

    float local = 0.f;

    // This wave's output row: window rr = w .. w+8 (all resident).
    {
        float SI[8], SJ[8], SI2[8], SJ2[8], SIJ[8];
        #pragma unroll
        for (int c = 0; c < 8; ++c) { SI[c]=0.f; SJ[c]=0.f; SI2[c]=0.f; SJ2[c]=0.f; SIJ[c]=0.f; }
        #pragma unroll
        for (int k = 0; k < 9; ++k) {
            const int sl = w + k;
            const float4 i0 = ring4[sl][0][lane];
            const float4 i1 = ring4[sl][0][64 + lane];
            const float4 j0 = ring4[sl][1][lane];
            const float4 j1 = ring4[sl][1][64 + lane];
            const float ai[8] = {i0.x, i0.y, i0.z, i0.w, i1.x, i1.y, i1.z, i1.w};
            const float bj[8] = {j0.x, j0.y, j0.z, j0.w, j1.x, j1.y, j1.z, j1.w};
            #pragma unroll
            for (int c = 0; c < 8; ++c) {
                SI[c] += ai[c];  SJ[c] += bj[c];
                SI2[c] = fmaf(ai[c], ai[c], SI2[c]);
                SJ2[c] = fmaf(bj[c], bj[c], SJ2[c]);
                SIJ[c] = fmaf(ai[c], bj[c], SIJ[c]);
            }
        }
        float BI[8], BJ[8], BI2[8], BJ2[8], BIJ[8];
        hbox(SI, BI); hbox(SJ, BJ); hbox(SI2, BI2); hbox(SJ2, BJ2); hbox(SIJ, BIJ);
        #pragma unroll
        for (int c = 0; c < 8; ++c) {
            const float tI = BI[c] * INV81;
            const float tJ = BJ[c] * INV81;
            const float cross = fmaf(-tI, BJ[c], BIJ[c]);
            const float Iv    = fmaf(-tI, BI[c], BI2[c]);
            const float Jv    = fmaf(-tJ, BJ[c], BJ2[c]);
            const float den   = fmaf(Iv, Jv, EPSF);
            local = fmaf(cross * cross, __builtin_amdgcn_rcpf(den), local);
        }
    }

    // wave reduction -> block reduction -> one plain store per block
    #pragma unroll
    for (int off = 32; off > 0; off >>= 1) local += __shfl_down(local, off);
    if (lane == 0) wsum[w] = local;
    __syncthreads();
    if (tid == 0) {
        float b = 0.f;
        #pragma unroll
        for (int k = 0; k < 8; ++k) b += wsum[k];
        part[blockIdx.x] = b;             // distinct address per block
    }
}

// 1 block, 1024 threads: reduce 1024 partials, write the scalar output.
__global__ __launch_bounds__(1024) void ncc_final(const float* __restrict__ part,
                                                  float* __restrict__ out) {
    __shared__ float s[16];
    const int tid  = threadIdx.x;
    const int lane = tid & 63;
    const int w    = tid >> 6;
    float v = part[tid];
    #pragma unroll
    for (int off = 32; off > 0; off >>= 1) v += __shfl_down(v, off);
    if (lane == 0) s[w] = v;
    __syncthreads();
    if (tid == 0) {
        float t = 0.f;
        #pragma unroll
        for (int k = 0; k < 16; ++k) t += s[k];
        out[0] = 1.0f - t * (1.0f / (float)((size_t)NIMG * HH * WW));
    }
}

extern "C" void kernel_launch(void* const* d_in, const int* in_sizes, int n_in,
                              void* d_out, int out_size, void* d_ws, size_t ws_size,
                              hipStream_t stream) {
    const float* I = (const float*)d_in[0];
    const float* J = (const float*)d_in[1];
    float* out  = (float*)d_out;
    float* part = (float*)d_ws;          // 1024 floats, fully rewritten each call

    // 1024 blocks = 16 images x 64 strips of 8 rows; 8 waves/block;
    // 64 KB LDS -> 2 resident/CU (4 waves/SIMD), 4 generations/CU overlap.
    ncc_main<<<1024, 512, 0, stream>>>(I, J, part);
    ncc_final<<<1, 1024, 0, stream>>>(part, out);
}